// Round 2
// baseline (86.900 us; speedup 1.0000x reference)
//
#include <hip/hip_runtime.h>
#include <math.h>

#define NQ 4
#define NL 6
#define DIM 16
#define BLOCK 256

// ---------------------------------------------------------------------------
// Kernel A (1 wave): the post-embedding circuit is batch-uniform -> collapse
// all 24 Rot gates + 24 CNOTs into one 16x16 complex matrix W by pushing the
// 16 basis columns through the gate chain (one column per lane, registers
// only). The embedding product state is mag_c * (-i)^popc(c) with mag_c real,
// so we fold the (-i)^popc(c) phase into column c of W; the batch kernel then
// only needs a complex-matrix x real-vector product.
// Layout in ws: wr[c*16+i], wi[c*16+i]  (c-major, phase-folded, transposed)
// ---------------------------------------------------------------------------
__global__ void build_w_kernel(const float* __restrict__ rot,
                               float* __restrict__ wr,
                               float* __restrict__ wi)
{
    const int c = threadIdx.x;
    if (c >= DIM) return;

    float sr[DIM], si[DIM];
#pragma unroll
    for (int i = 0; i < DIM; ++i) { sr[i] = (i == c) ? 1.0f : 0.0f; si[i] = 0.0f; }

#pragma unroll
    for (int l = 0; l < NL; ++l) {
#pragma unroll
        for (int q = 0; q < NQ; ++q) {
            const float phi = rot[(l * NQ + q) * 3 + 0];
            const float th  = rot[(l * NQ + q) * 3 + 1];
            const float om  = rot[(l * NQ + q) * 3 + 2];
            float st, ct; __sincosf(0.5f * th, &st, &ct);
            float sa, ca; __sincosf(0.5f * (phi + om), &sa, &ca);  // ep = ca - i sa
            float sb, cb; __sincosf(0.5f * (phi - om), &sb, &cb);  // em = cb + i sb
            const float u00r = ca * ct,  u00i = -sa * ct;
            const float u01r = -cb * st, u01i = -sb * st;
            const float u10r = cb * st,  u10i = -sb * st;
            const float u11r = ca * ct,  u11i = sa * ct;
            const int m = 1 << (3 - q);
#pragma unroll
            for (int i = 0; i < DIM; ++i) {
                if (!(i & m)) {
                    const int j = i | m;
                    const float a0r = sr[i], a0i = si[i];
                    const float a1r = sr[j], a1i = si[j];
                    sr[i] = u00r * a0r - u00i * a0i + u01r * a1r - u01i * a1i;
                    si[i] = u00r * a0i + u00i * a0r + u01r * a1i + u01i * a1r;
                    sr[j] = u10r * a0r - u10i * a0i + u11r * a1r - u11i * a1i;
                    si[j] = u10r * a0i + u10i * a0r + u11r * a1i + u11i * a1r;
                }
            }
        }
        const int r = l % (NQ - 1) + 1;
#pragma unroll
        for (int q = 0; q < NQ; ++q) {
            const int t = (q + r) & 3;
            const int cm = 1 << (3 - q);
            const int tm = 1 << (3 - t);
#pragma unroll
            for (int i = 0; i < DIM; ++i) {
                if ((i & cm) && !(i & tm)) {
                    const int j = i | tm;
                    float tr = sr[i]; sr[i] = sr[j]; sr[j] = tr;
                    float ti = si[i]; si[i] = si[j]; si[j] = ti;
                }
            }
        }
    }

    // fold the embedding phase (-i)^popc(c) of column c into W
    const int k = __popc(c) & 3;
    const float pr = (k == 0) ? 1.0f : ((k == 2) ? -1.0f : 0.0f);
    const float pm = (k == 3) ? 1.0f : ((k == 1) ? -1.0f : 0.0f);
#pragma unroll
    for (int i = 0; i < DIM; ++i) {
        wr[c * DIM + i] = pr * sr[i] - pm * si[i];
        wi[c * DIM + i] = pr * si[i] + pm * sr[i];
    }
}

// ---------------------------------------------------------------------------
// Kernel B: per sample, build the 16 real magnitudes of the embedded product
// state (24 mults from 4 sincos), multiply by the uniform phase-folded W
// (scalar loads -> SGPR operands), then Z-expectations from |amp|^2.
// ---------------------------------------------------------------------------
__global__ __launch_bounds__(BLOCK) void vqc_apply_kernel(
    const float* __restrict__ inputs,   // [B,4]
    const float* __restrict__ wr,       // [16][16] c-major
    const float* __restrict__ wi,
    float* __restrict__ out,            // [B,4]
    int batch)
{
    const int b = blockIdx.x * BLOCK + threadIdx.x;
    if (b >= batch) return;

    const float4 x = ((const float4*)inputs)[b];
    float c0, s0, c1, s1, c2, s2, c3, s3;
    __sincosf(0.5f * x.x, &s0, &c0);
    __sincosf(0.5f * x.y, &s1, &c1);
    __sincosf(0.5f * x.z, &s2, &c2);
    __sincosf(0.5f * x.w, &s3, &c3);

    // qubit q <-> bit (3-q); mag[i] = prod over qubits of (bit ? s : c)
    float m01[4] = {c0 * c1, c0 * s1, s0 * c1, s0 * s1};  // idx = (b3<<1)|b2
    float m23[4] = {c2 * c3, c2 * s3, s2 * c3, s2 * s3};  // idx = (b1<<1)|b0
    float mag[DIM];
#pragma unroll
    for (int i = 0; i < DIM; ++i) mag[i] = m01[i >> 2] * m23[i & 3];

    float ar[DIM], ai[DIM];
#pragma unroll
    for (int i = 0; i < DIM; ++i) { ar[i] = 0.0f; ai[i] = 0.0f; }
#pragma unroll
    for (int c = 0; c < DIM; ++c) {
        const float m = mag[c];
#pragma unroll
        for (int i = 0; i < DIM; ++i) {
            ar[i] = fmaf(wr[c * DIM + i], m, ar[i]);
            ai[i] = fmaf(wi[c * DIM + i], m, ai[i]);
        }
    }

    float e0 = 0.f, e1 = 0.f, e2 = 0.f, e3 = 0.f;
#pragma unroll
    for (int i = 0; i < DIM; ++i) {
        const float p = ar[i] * ar[i] + ai[i] * ai[i];
        e0 += ((i >> 3) & 1) ? -p : p;
        e1 += ((i >> 2) & 1) ? -p : p;
        e2 += ((i >> 1) & 1) ? -p : p;
        e3 += ((i >> 0) & 1) ? -p : p;
    }
    ((float4*)out)[b] = make_float4(e0, e1, e2, e3);
}

extern "C" void kernel_launch(void* const* d_in, const int* in_sizes, int n_in,
                              void* d_out, int out_size, void* d_ws, size_t ws_size,
                              hipStream_t stream) {
    const float* inputs = (const float*)d_in[0];   // [B,4] fp32
    const float* rot = (const float*)d_in[1];      // [6,4,3] fp32
    float* out = (float*)d_out;                    // [B,4] fp32
    float* wr = (float*)d_ws;                      // 256 floats
    float* wi = wr + DIM * DIM;                    // 256 floats
    const int batch = in_sizes[0] / NQ;

    build_w_kernel<<<1, 64, 0, stream>>>(rot, wr, wi);
    const int grid = (batch + BLOCK - 1) / BLOCK;
    vqc_apply_kernel<<<grid, BLOCK, 0, stream>>>(inputs, wr, wi, out, batch);
}

// Round 3
// 74.907 us; speedup vs baseline: 1.1601x; 1.1601x over previous
//
#include <hip/hip_runtime.h>
#include <math.h>

#define NQ 4
#define NL 6
#define DIM 16
#define BLOCK 256

// Single dispatch. Per block: lanes 0..15 of wave 0 collapse the batch-uniform
// part of the circuit (24 Rot + 24 CNOT) into a 16x16 complex matrix W in LDS
// (one basis column per lane, registers only), with the embedding phase
// (-i)^popc(c) folded into column c. Then every thread handles one sample:
// 16 real magnitudes (product state) -> complex matvec vs W (LDS broadcast
// reads, float2 -> v_pk_fma) -> Z expectations.
__global__ __launch_bounds__(BLOCK) void vqc_fused_kernel(
    const float* __restrict__ inputs,   // [B,4]
    const float* __restrict__ rot,      // [6,4,3]
    float* __restrict__ out,            // [B,4]
    int batch)
{
    __shared__ float2 W[DIM][DIM];  // W[c][i] = column c, row i (phase-folded)

    const int tid = threadIdx.x;
    if (tid < DIM) {
        const int c = tid;
        float sr[DIM], si[DIM];
#pragma unroll
        for (int i = 0; i < DIM; ++i) { sr[i] = (i == c) ? 1.0f : 0.0f; si[i] = 0.0f; }

#pragma unroll
        for (int l = 0; l < NL; ++l) {
#pragma unroll
            for (int q = 0; q < NQ; ++q) {
                const float phi = rot[(l * NQ + q) * 3 + 0];
                const float th  = rot[(l * NQ + q) * 3 + 1];
                const float om  = rot[(l * NQ + q) * 3 + 2];
                float st, ct; __sincosf(0.5f * th, &st, &ct);
                float sa, ca; __sincosf(0.5f * (phi + om), &sa, &ca);  // ep = ca - i sa
                float sb, cb; __sincosf(0.5f * (phi - om), &sb, &cb);  // em = cb + i sb
                const float u00r = ca * ct,  u00i = -sa * ct;
                const float u01r = -cb * st, u01i = -sb * st;
                const float u10r = cb * st,  u10i = -sb * st;
                const float u11r = ca * ct,  u11i = sa * ct;
                const int m = 1 << (3 - q);
#pragma unroll
                for (int i = 0; i < DIM; ++i) {
                    if (!(i & m)) {
                        const int j = i | m;
                        const float a0r = sr[i], a0i = si[i];
                        const float a1r = sr[j], a1i = si[j];
                        sr[i] = u00r * a0r - u00i * a0i + u01r * a1r - u01i * a1i;
                        si[i] = u00r * a0i + u00i * a0r + u01r * a1i + u01i * a1r;
                        sr[j] = u10r * a0r - u10i * a0i + u11r * a1r - u11i * a1i;
                        si[j] = u10r * a0i + u10i * a0r + u11r * a1i + u11i * a1r;
                    }
                }
            }
            const int r = l % (NQ - 1) + 1;
#pragma unroll
            for (int q = 0; q < NQ; ++q) {
                const int t = (q + r) & 3;
                const int cm = 1 << (3 - q);
                const int tm = 1 << (3 - t);
#pragma unroll
                for (int i = 0; i < DIM; ++i) {
                    if ((i & cm) && !(i & tm)) {
                        const int j = i | tm;
                        float tr = sr[i]; sr[i] = sr[j]; sr[j] = tr;
                        float ti = si[i]; si[i] = si[j]; si[j] = ti;
                    }
                }
            }
        }

        // fold embedding phase (-i)^popc(c): 0->(1,0) 1->(0,-1) 2->(-1,0) 3->(0,1)
        const int k = __popc(c) & 3;
        const float pr = (k == 0) ? 1.0f : ((k == 2) ? -1.0f : 0.0f);
        const float pm = (k == 3) ? 1.0f : ((k == 1) ? -1.0f : 0.0f);
#pragma unroll
        for (int i = 0; i < DIM; ++i) {
            W[c][i] = make_float2(pr * sr[i] - pm * si[i],
                                  pr * si[i] + pm * sr[i]);
        }
    }
    __syncthreads();

    const int b = blockIdx.x * BLOCK + tid;
    if (b >= batch) return;

    const float4 x = ((const float4*)inputs)[b];
    float c0, s0, c1, s1, c2, s2, c3, s3;
    __sincosf(0.5f * x.x, &s0, &c0);
    __sincosf(0.5f * x.y, &s1, &c1);
    __sincosf(0.5f * x.z, &s2, &c2);
    __sincosf(0.5f * x.w, &s3, &c3);

    // qubit q <-> bit (3-q); mag[i] = prod over qubits of (bit ? s : c)
    const float m01[4] = {c0 * c1, c0 * s1, s0 * c1, s0 * s1};  // (b3<<1)|b2
    const float m23[4] = {c2 * c3, c2 * s3, s2 * c3, s2 * s3};  // (b1<<1)|b0
    float mag[DIM];
#pragma unroll
    for (int i = 0; i < DIM; ++i) mag[i] = m01[i >> 2] * m23[i & 3];

    float2 acc[DIM];
#pragma unroll
    for (int i = 0; i < DIM; ++i) acc[i] = make_float2(0.0f, 0.0f);
#pragma unroll
    for (int c = 0; c < DIM; ++c) {
        const float m = mag[c];
#pragma unroll
        for (int i = 0; i < DIM; ++i) {
            const float2 w = W[c][i];
            acc[i].x = fmaf(w.x, m, acc[i].x);
            acc[i].y = fmaf(w.y, m, acc[i].y);
        }
    }

    float e0 = 0.f, e1 = 0.f, e2 = 0.f, e3 = 0.f;
#pragma unroll
    for (int i = 0; i < DIM; ++i) {
        const float p = acc[i].x * acc[i].x + acc[i].y * acc[i].y;
        e0 += ((i >> 3) & 1) ? -p : p;
        e1 += ((i >> 2) & 1) ? -p : p;
        e2 += ((i >> 1) & 1) ? -p : p;
        e3 += ((i >> 0) & 1) ? -p : p;
    }
    ((float4*)out)[b] = make_float4(e0, e1, e2, e3);
}

extern "C" void kernel_launch(void* const* d_in, const int* in_sizes, int n_in,
                              void* d_out, int out_size, void* d_ws, size_t ws_size,
                              hipStream_t stream) {
    const float* inputs = (const float*)d_in[0];   // [B,4] fp32
    const float* rot = (const float*)d_in[1];      // [6,4,3] fp32
    float* out = (float*)d_out;                    // [B,4] fp32
    const int batch = in_sizes[0] / NQ;
    const int grid = (batch + BLOCK - 1) / BLOCK;
    vqc_fused_kernel<<<grid, BLOCK, 0, stream>>>(inputs, rot, out, batch);
}